// Round 5
// baseline (174.638 us; speedup 1.0000x reference)
//
#include <hip/hip_runtime.h>
#include <math.h>

#define B      16
#define KN     80000
#define MASKW  32
#define MASKPX 1024
#define NCLS   3
#define BN     95
#define NP     100
#define NCOV   5
#define FW     128
#define FCH    512
#define FPX    16384
#define CIN    515
#define FSTR   516
#define HID    256
#define NBIN   4096
#define CCAP   2048
#define PBM    8

#define NTW    (FSTR*HID + HID*HID + HID*HID)   // 263168
#define NMASK  (B*NCLS*MASKPX)                  // 49152
#define PREP_TOT (NTW + NMASK)                  // 312320
#define SEL_B  16
#define PREP_BLOCKS 64
#define PREP_STRIDE (PREP_BLOCKS * 1024)
#define GRID_FRONT (SEL_B + PREP_BLOCKS)

// ---- ws layout (float offsets) ----
#define WS_U   0
#define WS_PTS (WS_U + B*KN)
#define WS_WT1 (WS_PTS + B*NP*2)
#define WS_WT2 (WS_WT1 + FSTR*HID)
#define WS_WT3 (WS_WT2 + HID*HID)
#define WS_F   (WS_WT3 + HID*HID)
// end: WS_F + 1600*516 ≈ 2.37 M floats (~9.5 MB)

// K_FRONT: blocks 0..15 = fused per-batch point selection
//          blocks 16..79 = grid-stride weight transpose + mask passthrough
__global__ __launch_bounds__(1024) void k_front(
        const float* __restrict__ mask, const float* __restrict__ og,
        const float* __restrict__ cov,
        const float* __restrict__ w1, const float* __restrict__ w2,
        const float* __restrict__ w3,
        float* __restrict__ uws, float* __restrict__ pts_ws,
        float* __restrict__ pts_out,
        float* __restrict__ wt1, float* __restrict__ wt2, float* __restrict__ wt3,
        float* __restrict__ out_mask) {
    __shared__ float ps0[MASKPX];
    __shared__ float ps1[MASKPX];
    __shared__ int   hist[NBIN];
    __shared__ float cv[CCAP];
    __shared__ int   ci[CCAP];
    __shared__ int   s_cnt;
    __shared__ float s_T;
    int tid = threadIdx.x;

    if (blockIdx.x >= SEL_B) {
        // ---- prep path: grid-stride elementwise ----
        for (int j0 = (blockIdx.x - SEL_B) * 1024 + tid; j0 < PREP_TOT;
             j0 += PREP_STRIDE) {
            int j = j0;
            if (j < FSTR * HID) {
                int c = j >> 8, o = j & 255;
                wt1[j] = (c < CIN) ? w1[o * CIN + c] : 0.0f;
                continue;
            }
            j -= FSTR * HID;
            if (j < HID * HID) {
                int c = j >> 8, o = j & 255;
                wt2[j] = w2[o * HID + c];
                continue;
            }
            j -= HID * HID;
            if (j < HID * HID) {
                int c = j >> 8, o = j & 255;
                wt3[j] = w3[o * HID + c];
                continue;
            }
            j -= HID * HID;
            out_mask[j] = mask[j];
        }
        return;
    }

    // ---- select path, batch b ----
    int b = blockIdx.x;
    // softmax top-2 into LDS (identical fp op sequence to prior rounds)
    for (int pix = tid; pix < MASKPX; pix += 1024) {
        const float* mb = mask + (size_t)b * NCLS * MASKPX + pix;
        float a0 = mb[0], a1 = mb[MASKPX], a2 = mb[2 * MASKPX];
        float m = fmaxf(fmaxf(a0, a1), a2);
        float e0 = (float)exp((double)(a0 - m));
        float e1 = (float)exp((double)(a1 - m));
        float e2 = (float)exp((double)(a2 - m));
        float s = (e0 + e1) + e2;
        float p0 = e0 / s, p1 = e1 / s, p2 = e2 / s;
        float hi  = fmaxf(fmaxf(p0, p1), p2);
        float mid = fmaxf(fminf(p0, p1), fminf(fmaxf(p0, p1), p2));
        ps0[pix] = hi;
        ps1[pix] = mid;
    }
    for (int i = tid; i < NBIN; i += 1024) hist[i] = 0;
    if (tid == 0) s_cnt = 0;
    __syncthreads();

    // u + histogram pass (u op sequence identical to prior rounds)
    float* ub = uws + (size_t)b * KN;
    const float2* ogb = (const float2*)(og + (size_t)b * KN * 2);
    for (int i = tid; i < KN; i += 1024) {
        float2 q = ogb[i];
        float cx = q.x, cy = q.y;
        float gx = 2.0f * cx - 1.0f, gy = 2.0f * cy - 1.0f;
        float ix = ((gx + 1.0f) * 32.0f - 1.0f) * 0.5f;
        float iy = ((gy + 1.0f) * 32.0f - 1.0f) * 0.5f;
        float x0 = floorf(ix), y0 = floorf(iy);
        float wx1 = ix - x0, wy1 = iy - y0;
        float wx0 = 1.0f - wx1, wy0 = 1.0f - wy1;
        float s0 = 0.f, s1 = 0.f;
#define TAP(XC, YC, WV) { \
        float xf = (XC), yf = (YC); \
        float valid = (xf >= 0.f && xf <= 31.f && yf >= 0.f && yf <= 31.f) ? 1.f : 0.f; \
        int xi = (int)fminf(fmaxf(xf, 0.f), 31.f); \
        int yi = (int)fminf(fmaxf(yf, 0.f), 31.f); \
        float w = (WV) * valid; \
        int off = yi * 32 + xi; \
        s0 += ps0[off] * w; s1 += ps1[off] * w; }
        TAP(x0,        y0,        wx0 * wy0)
        TAP(x0 + 1.0f, y0,        wx1 * wy0)
        TAP(x0,        y0 + 1.0f, wx0 * wy1)
        TAP(x0 + 1.0f, y0 + 1.0f, wx1 * wy1)
#undef TAP
        float v = -(s0 - s1);
        ub[i] = v;
        int bin = (int)((v + 1.0f) * 4096.0f);
        bin = bin < 0 ? 0 : (bin > NBIN - 1 ? NBIN - 1 : bin);
        atomicAdd(&hist[bin], 1);
    }
    __syncthreads();

    // two-level wave-parallel suffix scan to find threshold bin tb
    if (tid < 64) {
        int sup = 0;
#pragma unroll
        for (int j = 0; j < 64; ++j) sup += hist[(tid << 6) + j];
        int cum = sup;
#pragma unroll
        for (int d = 1; d < 64; d <<= 1) {
            int o = __shfl_down(cum, d, 64);
            if (tid + d < 64) cum += o;
        }
        unsigned long long m1 = __ballot(cum >= BN);
        int SB = 63 - __builtin_clzll(m1);
        int lane2 = (SB + 1) & 63;
        int above = __shfl(cum, lane2, 64);
        if (SB == 63) above = 0;
        int h = hist[(SB << 6) + tid];
        int cumf = h;
#pragma unroll
        for (int d = 1; d < 64; d <<= 1) {
            int o = __shfl_down(cumf, d, 64);
            if (tid + d < 64) cumf += o;
        }
        unsigned long long m2 = __ballot(cumf + above >= BN);
        int t = 63 - __builtin_clzll(m2);
        int tb = (SB << 6) + t;
        if (tid == 0)
            s_T = (tb > 0) ? ((float)(tb - 1) * (1.0f / 4096.0f) - 1.0f) : -2.0f;
    }
    __syncthreads();

    // collect candidates >= T (u re-read, L2-hot)
    float T = s_T;
    for (int i = tid; i < KN; i += 1024) {
        float v = ub[i];
        if (v >= T) {
            int pos = atomicAdd(&s_cnt, 1);
            if (pos < CCAP) { cv[pos] = v; ci[pos] = i; }
        }
    }
    __syncthreads();
    int n = s_cnt; if (n > CCAP) n = CCAP;
    int M = 128; while (M < n) M <<= 1;
    for (int i = tid; i < M; i += 1024)
        if (i >= n) { cv[i] = -3.0f; ci[i] = 0x7fffffff; }
    __syncthreads();
    // bitonic sort: descending by (value, then lower index first)
    for (int k = 2; k <= M; k <<= 1) {
        for (int j = k >> 1; j > 0; j >>= 1) {
            for (int idx = tid; idx < M; idx += 1024) {
                int l = idx ^ j;
                if (l > idx) {
                    float va = cv[idx], vb = cv[l];
                    int ia = ci[idx], ib = ci[l];
                    bool l_first = (vb > va) || (vb == va && ib < ia);
                    bool dirDesc = ((idx & k) == 0);
                    if (l_first == dirDesc) {
                        cv[idx] = vb; cv[l] = va;
                        ci[idx] = ib; ci[l] = ia;
                    }
                }
            }
            __syncthreads();
        }
    }
    if (tid < BN) {
        int gi = ci[tid];
        float px = og[((size_t)b * KN + gi) * 2];
        float py = og[((size_t)b * KN + gi) * 2 + 1];
        int o = (b * NP + tid) * 2;
        pts_ws[o] = px; pts_ws[o + 1] = py;
        pts_out[o] = px; pts_out[o + 1] = py;
    } else if (tid < NP) {
        int j = tid - BN;
        float px = cov[((size_t)b * NCOV + j) * 2];
        float py = cov[((size_t)b * NCOV + j) * 2 + 1];
        int o = (b * NP + tid) * 2;
        pts_ws[o] = px; pts_ws[o + 1] = py;
        pts_out[o] = px; pts_out[o + 1] = py;
    }
}

// K_GATHER: one block per point, 256 threads; pure scatter-gather at max TLP.
__global__ __launch_bounds__(256) void k_gather(
        const float* __restrict__ maskp, const float* __restrict__ feat,
        const float* __restrict__ pts, float* __restrict__ F) {
    int p = blockIdx.x;            // 0..1599
    int b = p / NP;
    int tid = threadIdx.x;
    float cx = pts[(size_t)p * 2], cy = pts[(size_t)p * 2 + 1];
    float gx = 2.0f * cx - 1.0f, gy = 2.0f * cy - 1.0f;
    float ixf = ((gx + 1.0f) * 128.0f - 1.0f) * 0.5f;
    float iyf = ((gy + 1.0f) * 128.0f - 1.0f) * 0.5f;
    float x0f = floorf(ixf), y0f = floorf(iyf);
    float wx1f = ixf - x0f, wy1f = iyf - y0f;
    float wx0f = 1.0f - wx1f, wy0f = 1.0f - wy1f;

    if (tid < 4) {    // coarse channels + pad
        if (tid < 3) {
            float ixm = ((gx + 1.0f) * 32.0f - 1.0f) * 0.5f;
            float iym = ((gy + 1.0f) * 32.0f - 1.0f) * 0.5f;
            float x0m = floorf(ixm), y0m = floorf(iym);
            float wx1m = ixm - x0m, wy1m = iym - y0m;
            float wx0m = 1.0f - wx1m, wy0m = 1.0f - wy1m;
            const float* img = maskp + ((size_t)b * NCLS + tid) * MASKPX;
            float acc = 0.f;
#define TAPM(XC, YC, WV) { \
            float xf = (XC), yf = (YC); \
            float valid = (xf >= 0.f && xf <= 31.f && yf >= 0.f && yf <= 31.f) ? 1.f : 0.f; \
            int xi = (int)fminf(fmaxf(xf, 0.f), 31.f); \
            int yi = (int)fminf(fmaxf(yf, 0.f), 31.f); \
            acc += img[yi * 32 + xi] * ((WV) * valid); }
            TAPM(x0m,        y0m,        wx0m * wy0m)
            TAPM(x0m + 1.0f, y0m,        wx1m * wy0m)
            TAPM(x0m,        y0m + 1.0f, wx0m * wy1m)
            TAPM(x0m + 1.0f, y0m + 1.0f, wx1m * wy1m)
#undef TAPM
            F[(size_t)p * FSTR + tid] = acc;
        } else {
            F[(size_t)p * FSTR + CIN] = 0.0f;   // pad channel
        }
    }

    // fine channels: 2 per thread, 8 independent scattered loads in flight
#pragma unroll
    for (int cc = 0; cc < 2; ++cc) {
        int c = tid + cc * 256;
        const float* img = feat + ((size_t)b * FCH + c) * FPX;
        float acc = 0.f;
#define TAPF(XC, YC, WV) { \
        float xf = (XC), yf = (YC); \
        float valid = (xf >= 0.f && xf <= 127.f && yf >= 0.f && yf <= 127.f) ? 1.f : 0.f; \
        int xi = (int)fminf(fmaxf(xf, 0.f), 127.f); \
        int yi = (int)fminf(fmaxf(yf, 0.f), 127.f); \
        acc += img[yi * 128 + xi] * ((WV) * valid); }
        TAPF(x0f,        y0f,        wx0f * wy0f)
        TAPF(x0f + 1.0f, y0f,        wx1f * wy0f)
        TAPF(x0f,        y0f + 1.0f, wx0f * wy1f)
        TAPF(x0f + 1.0f, y0f + 1.0f, wx1f * wy1f)
#undef TAPF
        F[(size_t)p * FSTR + c + 3] = acc;
    }
}

// K_MLP: fused 4-layer MLP, PBM=8 points per block (R2-verified structure).
__global__ __launch_bounds__(256) void k_mlp(const float* __restrict__ F,
                                             const float* __restrict__ wt1,
                                             const float* __restrict__ wt2,
                                             const float* __restrict__ wt3,
                                             const float* __restrict__ w4,
                                             const float* __restrict__ b4,
                                             float* __restrict__ rend) {
    __shared__ float Fl[PBM][FSTR];
    __shared__ float hA[PBM][HID];
    __shared__ float hB[PBM][HID];
    int tid = threadIdx.x;
    int p0 = blockIdx.x * PBM;
    {   // coalesced float4 load of 8 x 516 inputs
        const float4* src = (const float4*)(F + (size_t)p0 * FSTR);
        float4* dst = (float4*)&Fl[0][0];
        for (int i = tid; i < PBM * FSTR / 4; i += 256) dst[i] = src[i];
    }
    __syncthreads();
    {   // layer 1: 515(+1 pad) -> 256, relu
        int o = tid;
        float acc[PBM];
#pragma unroll
        for (int p = 0; p < PBM; ++p) acc[p] = 0.f;
        for (int c4 = 0; c4 < FSTR / 4; ++c4) {
            float wa = wt1[(c4 * 4 + 0) * HID + o];
            float wb = wt1[(c4 * 4 + 1) * HID + o];
            float wc = wt1[(c4 * 4 + 2) * HID + o];
            float wd = wt1[(c4 * 4 + 3) * HID + o];
#pragma unroll
            for (int p = 0; p < PBM; ++p) {
                float4 f = *(const float4*)&Fl[p][c4 * 4];
                acc[p] = fmaf(wa, f.x, acc[p]);
                acc[p] = fmaf(wb, f.y, acc[p]);
                acc[p] = fmaf(wc, f.z, acc[p]);
                acc[p] = fmaf(wd, f.w, acc[p]);
            }
        }
#pragma unroll
        for (int p = 0; p < PBM; ++p) hA[p][o] = fmaxf(acc[p], 0.f);
    }
    __syncthreads();
    {   // layer 2
        int o = tid;
        float acc[PBM];
#pragma unroll
        for (int p = 0; p < PBM; ++p) acc[p] = 0.f;
        for (int c4 = 0; c4 < HID / 4; ++c4) {
            float wa = wt2[(c4 * 4 + 0) * HID + o];
            float wb = wt2[(c4 * 4 + 1) * HID + o];
            float wc = wt2[(c4 * 4 + 2) * HID + o];
            float wd = wt2[(c4 * 4 + 3) * HID + o];
#pragma unroll
            for (int p = 0; p < PBM; ++p) {
                float4 f = *(const float4*)&hA[p][c4 * 4];
                acc[p] = fmaf(wa, f.x, acc[p]);
                acc[p] = fmaf(wb, f.y, acc[p]);
                acc[p] = fmaf(wc, f.z, acc[p]);
                acc[p] = fmaf(wd, f.w, acc[p]);
            }
        }
#pragma unroll
        for (int p = 0; p < PBM; ++p) hB[p][o] = fmaxf(acc[p], 0.f);
    }
    __syncthreads();
    {   // layer 3
        int o = tid;
        float acc[PBM];
#pragma unroll
        for (int p = 0; p < PBM; ++p) acc[p] = 0.f;
        for (int c4 = 0; c4 < HID / 4; ++c4) {
            float wa = wt3[(c4 * 4 + 0) * HID + o];
            float wb = wt3[(c4 * 4 + 1) * HID + o];
            float wc = wt3[(c4 * 4 + 2) * HID + o];
            float wd = wt3[(c4 * 4 + 3) * HID + o];
#pragma unroll
            for (int p = 0; p < PBM; ++p) {
                float4 f = *(const float4*)&hB[p][c4 * 4];
                acc[p] = fmaf(wa, f.x, acc[p]);
                acc[p] = fmaf(wb, f.y, acc[p]);
                acc[p] = fmaf(wc, f.z, acc[p]);
                acc[p] = fmaf(wd, f.w, acc[p]);
            }
        }
#pragma unroll
        for (int p = 0; p < PBM; ++p) hA[p][o] = fmaxf(acc[p], 0.f);
    }
    __syncthreads();
    if (tid < 3 * PBM) {  // layer 4: 256 -> 3, + b4
        int o = tid % 3, p = tid / 3;
        float acc = 0.f;
        const float* wr = w4 + (size_t)o * HID;
        for (int c = 0; c < HID; ++c) acc += wr[c] * hA[p][c];
        acc += b4[o];
        int gp = p0 + p;
        int b = gp / NP, n = gp % NP;
        rend[(size_t)b * (NCLS * NP) + o * NP + n] = acc;
    }
}

extern "C" void kernel_launch(void* const* d_in, const int* in_sizes, int n_in,
                              void* d_out, int out_size, void* d_ws, size_t ws_size,
                              hipStream_t stream) {
    // inputs: 0:x(unused) 1:feature 2:mask 3:over_gen 4:coverage 5:w1 6:w2 7:w3 8:w4 9:b4
    const float* feature  = (const float*)d_in[1];
    const float* mask     = (const float*)d_in[2];
    const float* over_gen = (const float*)d_in[3];
    const float* coverage = (const float*)d_in[4];
    const float* w1 = (const float*)d_in[5];
    const float* w2 = (const float*)d_in[6];
    const float* w3 = (const float*)d_in[7];
    const float* w4 = (const float*)d_in[8];
    const float* b4 = (const float*)d_in[9];
    float* out = (float*)d_out;
    float* ws  = (float*)d_ws;

    float* uws = ws + WS_U;
    float* pts = ws + WS_PTS;
    float* wt1 = ws + WS_WT1;
    float* wt2 = ws + WS_WT2;
    float* wt3 = ws + WS_WT3;
    float* Fws = ws + WS_F;

    // out layout: rend[4800] | points[3200] | mask[49152]
    float* out_rend = out;
    float* out_pts  = out + 4800;
    float* out_mask = out + 8000;

    k_front<<<GRID_FRONT, 1024, 0, stream>>>(mask, over_gen, coverage,
                                             w1, w2, w3,
                                             uws, pts, out_pts,
                                             wt1, wt2, wt3, out_mask);
    k_gather<<<B * NP, 256, 0, stream>>>(mask, feature, pts, Fws);
    k_mlp<<<(B * NP) / PBM, 256, 0, stream>>>(Fws, wt1, wt2, wt3, w4, b4, out_rend);
}

// Round 6
// 114.463 us; speedup vs baseline: 1.5257x; 1.5257x over previous
//
#include <hip/hip_runtime.h>
#include <math.h>

#define B      16
#define KN     80000
#define MASKW  32
#define MASKPX 1024
#define NCLS   3
#define BN     95
#define NP     100
#define NCOV   5
#define FW     128
#define FCH    512
#define FPX    16384
#define CIN    515
#define FSTR   516
#define HID    256
#define NBIN   4096
#define CCAP   2048
#define PB     4

#define NTW    (FSTR*HID + HID*HID + HID*HID)   // 263168
#define NMASK  (B*NCLS*MASKPX)                  // 49152
#define PREP_TOT (NTW + NMASK)                  // 312320
#define UBLK   8                                 // u-pass blocks per batch
#define KN_PER (KN / UBLK)                       // 10000
#define SEL_FEED (B * UBLK)                      // 128
#define PREP_BLOCKS 64
#define PREP_STRIDE (PREP_BLOCKS * 1024)
#define GRID_U (SEL_FEED + PREP_BLOCKS)          // 192

// ---- ws layout (float offsets) ----
#define WS_U    0
#define WS_PTS  (WS_U + B*KN)
#define WS_WT1  (WS_PTS + B*NP*2)
#define WS_WT2  (WS_WT1 + FSTR*HID)
#define WS_WT3  (WS_WT2 + HID*HID)
#define WS_HIST (WS_WT3 + HID*HID)               // B*UBLK*NBIN ints
// end: WS_HIST + 16*8*4096 ≈ 2.07 M floats (~8.3 MB)

// K_U: blocks 0..127 = per-batch-slice u + private histogram
//      blocks 128..191 = grid-stride weight transpose + mask passthrough
__global__ __launch_bounds__(1024) void k_u(
        const float* __restrict__ mask, const float* __restrict__ og,
        const float* __restrict__ w1, const float* __restrict__ w2,
        const float* __restrict__ w3,
        float* __restrict__ uws, int* __restrict__ hist_g,
        float* __restrict__ wt1, float* __restrict__ wt2, float* __restrict__ wt3,
        float* __restrict__ out_mask) {
    __shared__ float ps0[MASKPX];
    __shared__ float ps1[MASKPX];
    __shared__ int   hist[NBIN];
    int tid = threadIdx.x;

    if (blockIdx.x >= SEL_FEED) {
        // ---- prep path: grid-stride elementwise ----
        for (int j0 = (blockIdx.x - SEL_FEED) * 1024 + tid; j0 < PREP_TOT;
             j0 += PREP_STRIDE) {
            int j = j0;
            if (j < FSTR * HID) {
                int c = j >> 8, o = j & 255;
                wt1[j] = (c < CIN) ? w1[o * CIN + c] : 0.0f;
                continue;
            }
            j -= FSTR * HID;
            if (j < HID * HID) {
                int c = j >> 8, o = j & 255;
                wt2[j] = w2[o * HID + c];
                continue;
            }
            j -= HID * HID;
            if (j < HID * HID) {
                int c = j >> 8, o = j & 255;
                wt3[j] = w3[o * HID + c];
                continue;
            }
            j -= HID * HID;
            out_mask[j] = mask[j];
        }
        return;
    }

    int b = blockIdx.x >> 3, sub = blockIdx.x & 7;
    // softmax top-2 into LDS (identical fp op sequence to prior rounds)
    {
        int pix = tid;
        const float* mb = mask + (size_t)b * NCLS * MASKPX + pix;
        float a0 = mb[0], a1 = mb[MASKPX], a2 = mb[2 * MASKPX];
        float m = fmaxf(fmaxf(a0, a1), a2);
        float e0 = (float)exp((double)(a0 - m));
        float e1 = (float)exp((double)(a1 - m));
        float e2 = (float)exp((double)(a2 - m));
        float s = (e0 + e1) + e2;
        float p0 = e0 / s, p1 = e1 / s, p2 = e2 / s;
        float hi  = fmaxf(fmaxf(p0, p1), p2);
        float mid = fmaxf(fminf(p0, p1), fminf(fmaxf(p0, p1), p2));
        ps0[pix] = hi;
        ps1[pix] = mid;
    }
    for (int i = tid; i < NBIN; i += 1024) hist[i] = 0;
    __syncthreads();

    // u + private histogram over this block's 10000-point slice
    float* ub = uws + (size_t)b * KN;
    const float2* ogb = (const float2*)(og + (size_t)b * KN * 2);
    int base = sub * KN_PER;
    for (int i = tid; i < KN_PER; i += 1024) {
        int gi = base + i;
        float2 q = ogb[gi];
        float cx = q.x, cy = q.y;
        float gx = 2.0f * cx - 1.0f, gy = 2.0f * cy - 1.0f;
        float ix = ((gx + 1.0f) * 32.0f - 1.0f) * 0.5f;
        float iy = ((gy + 1.0f) * 32.0f - 1.0f) * 0.5f;
        float x0 = floorf(ix), y0 = floorf(iy);
        float wx1 = ix - x0, wy1 = iy - y0;
        float wx0 = 1.0f - wx1, wy0 = 1.0f - wy1;
        float s0 = 0.f, s1 = 0.f;
#define TAP(XC, YC, WV) { \
        float xf = (XC), yf = (YC); \
        float valid = (xf >= 0.f && xf <= 31.f && yf >= 0.f && yf <= 31.f) ? 1.f : 0.f; \
        int xi = (int)fminf(fmaxf(xf, 0.f), 31.f); \
        int yi = (int)fminf(fmaxf(yf, 0.f), 31.f); \
        float w = (WV) * valid; \
        int off = yi * 32 + xi; \
        s0 += ps0[off] * w; s1 += ps1[off] * w; }
        TAP(x0,        y0,        wx0 * wy0)
        TAP(x0 + 1.0f, y0,        wx1 * wy0)
        TAP(x0,        y0 + 1.0f, wx0 * wy1)
        TAP(x0 + 1.0f, y0 + 1.0f, wx1 * wy1)
#undef TAP
        float v = -(s0 - s1);
        ub[gi] = v;
        int bin = (int)((v + 1.0f) * 4096.0f);
        bin = bin < 0 ? 0 : (bin > NBIN - 1 ? NBIN - 1 : bin);
        atomicAdd(&hist[bin], 1);
    }
    __syncthreads();
    int* hg = hist_g + (size_t)blockIdx.x * NBIN;
    for (int i = tid; i < NBIN; i += 1024) hg[i] = hist[i];
}

// K_SEL: 16 blocks; sum histogram slices, scan, collect, sort, emit points.
__global__ __launch_bounds__(1024) void k_sel(
        const float* __restrict__ uws, const float* __restrict__ og,
        const float* __restrict__ cov, const int* __restrict__ hist_g,
        float* __restrict__ pts_ws, float* __restrict__ pts_out) {
    __shared__ int   hist[NBIN];
    __shared__ float cv[CCAP];
    __shared__ int   ci[CCAP];
    __shared__ int   s_cnt;
    __shared__ float s_T;
    int tid = threadIdx.x;
    int b = blockIdx.x;

    // sum the 8 per-slice histograms
    const int* hg = hist_g + (size_t)b * UBLK * NBIN;
    for (int bin = tid; bin < NBIN; bin += 1024) {
        int t = 0;
#pragma unroll
        for (int s = 0; s < UBLK; ++s) t += hg[s * NBIN + bin];
        hist[bin] = t;
    }
    if (tid == 0) s_cnt = 0;
    __syncthreads();

    // two-level wave-parallel suffix scan to find threshold bin tb
    if (tid < 64) {
        int sup = 0;
#pragma unroll
        for (int j = 0; j < 64; ++j) sup += hist[(tid << 6) + j];
        int cum = sup;
#pragma unroll
        for (int d = 1; d < 64; d <<= 1) {
            int o = __shfl_down(cum, d, 64);
            if (tid + d < 64) cum += o;
        }
        unsigned long long m1 = __ballot(cum >= BN);
        int SB = 63 - __builtin_clzll(m1);
        int lane2 = (SB + 1) & 63;
        int above = __shfl(cum, lane2, 64);
        if (SB == 63) above = 0;
        int h = hist[(SB << 6) + tid];
        int cumf = h;
#pragma unroll
        for (int d = 1; d < 64; d <<= 1) {
            int o = __shfl_down(cumf, d, 64);
            if (tid + d < 64) cumf += o;
        }
        unsigned long long m2 = __ballot(cumf + above >= BN);
        int t = 63 - __builtin_clzll(m2);
        int tb = (SB << 6) + t;
        if (tid == 0)
            s_T = (tb > 0) ? ((float)(tb - 1) * (1.0f / 4096.0f) - 1.0f) : -2.0f;
    }
    __syncthreads();

    // collect candidates >= T (u L2-resident)
    float T = s_T;
    const float* ub = uws + (size_t)b * KN;
    for (int i = tid; i < KN; i += 1024) {
        float v = ub[i];
        if (v >= T) {
            int pos = atomicAdd(&s_cnt, 1);
            if (pos < CCAP) { cv[pos] = v; ci[pos] = i; }
        }
    }
    __syncthreads();
    int n = s_cnt; if (n > CCAP) n = CCAP;
    int M = 128; while (M < n) M <<= 1;
    for (int i = tid; i < M; i += 1024)
        if (i >= n) { cv[i] = -3.0f; ci[i] = 0x7fffffff; }
    __syncthreads();
    // bitonic sort: descending by (value, then lower index first)
    for (int k = 2; k <= M; k <<= 1) {
        for (int j = k >> 1; j > 0; j >>= 1) {
            for (int idx = tid; idx < M; idx += 1024) {
                int l = idx ^ j;
                if (l > idx) {
                    float va = cv[idx], vb = cv[l];
                    int ia = ci[idx], ib = ci[l];
                    bool l_first = (vb > va) || (vb == va && ib < ia);
                    bool dirDesc = ((idx & k) == 0);
                    if (l_first == dirDesc) {
                        cv[idx] = vb; cv[l] = va;
                        ci[idx] = ib; ci[l] = ia;
                    }
                }
            }
            __syncthreads();
        }
    }
    if (tid < BN) {
        int gi = ci[tid];
        float px = og[((size_t)b * KN + gi) * 2];
        float py = og[((size_t)b * KN + gi) * 2 + 1];
        int o = (b * NP + tid) * 2;
        pts_ws[o] = px; pts_ws[o + 1] = py;
        pts_out[o] = px; pts_out[o + 1] = py;
    } else if (tid < NP) {
        int j = tid - BN;
        float px = cov[((size_t)b * NCOV + j) * 2];
        float py = cov[((size_t)b * NCOV + j) * 2 + 1];
        int o = (b * NP + tid) * 2;
        pts_ws[o] = px; pts_ws[o + 1] = py;
        pts_out[o] = px; pts_out[o + 1] = py;
    }
}

// K_BACK: fused gather (coarse from mask, fine from feature) + 4-layer MLP.
// PB=4 points/block, 400 blocks (R4-measured best).
__global__ __launch_bounds__(256) void k_back(
        const float* __restrict__ maskp, const float* __restrict__ feat,
        const float* __restrict__ pts,
        const float* __restrict__ wt1, const float* __restrict__ wt2,
        const float* __restrict__ wt3, const float* __restrict__ w4,
        const float* __restrict__ b4, float* __restrict__ rend) {
    __shared__ float Fl[PB][FSTR];
    __shared__ float hA[PB][HID];
    __shared__ float hB[PB][HID];
    __shared__ float pp[PB][8];
    int tid = threadIdx.x;
    int p0 = blockIdx.x * PB;

    if (tid < PB) {   // per-point sampling params
        int gp = p0 + tid;
        float cx = pts[(size_t)gp * 2], cy = pts[(size_t)gp * 2 + 1];
        float gx = 2.0f * cx - 1.0f, gy = 2.0f * cy - 1.0f;
        float ixf = ((gx + 1.0f) * 128.0f - 1.0f) * 0.5f;
        float iyf = ((gy + 1.0f) * 128.0f - 1.0f) * 0.5f;
        float x0f = floorf(ixf), y0f = floorf(iyf);
        pp[tid][0] = x0f; pp[tid][1] = y0f;
        pp[tid][2] = ixf - x0f; pp[tid][3] = iyf - y0f;
        float ixm = ((gx + 1.0f) * 32.0f - 1.0f) * 0.5f;
        float iym = ((gy + 1.0f) * 32.0f - 1.0f) * 0.5f;
        float x0m = floorf(ixm), y0m = floorf(iym);
        pp[tid][4] = x0m; pp[tid][5] = y0m;
        pp[tid][6] = ixm - x0m; pp[tid][7] = iym - y0m;
    }
    __syncthreads();

    if (tid < PB * 4) {   // coarse channels + pad
        int p = tid >> 2, c = tid & 3;
        if (c < 3) {
            int gp = p0 + p, b = gp / NP;
            float x0m = pp[p][4], y0m = pp[p][5];
            float wx1m = pp[p][6], wy1m = pp[p][7];
            float wx0m = 1.0f - wx1m, wy0m = 1.0f - wy1m;
            const float* img = maskp + ((size_t)b * NCLS + c) * MASKPX;
            float acc = 0.f;
#define TAPM(XC, YC, WV) { \
            float xf = (XC), yf = (YC); \
            float valid = (xf >= 0.f && xf <= 31.f && yf >= 0.f && yf <= 31.f) ? 1.f : 0.f; \
            int xi = (int)fminf(fmaxf(xf, 0.f), 31.f); \
            int yi = (int)fminf(fmaxf(yf, 0.f), 31.f); \
            acc += img[yi * 32 + xi] * ((WV) * valid); }
            TAPM(x0m,        y0m,        wx0m * wy0m)
            TAPM(x0m + 1.0f, y0m,        wx1m * wy0m)
            TAPM(x0m,        y0m + 1.0f, wx0m * wy1m)
            TAPM(x0m + 1.0f, y0m + 1.0f, wx1m * wy1m)
#undef TAPM
            Fl[p][c] = acc;
        } else {
            Fl[p][CIN] = 0.0f;   // pad channel
        }
    }

    // fine channels: 4 pts x 512 ch = 8 per thread, 4 independent loads each
#pragma unroll 4
    for (int i = tid; i < PB * FCH; i += 256) {
        int p = i >> 9, c = i & 511;
        int gp = p0 + p, b = gp / NP;
        float x0f = pp[p][0], y0f = pp[p][1];
        float wx1f = pp[p][2], wy1f = pp[p][3];
        float wx0f = 1.0f - wx1f, wy0f = 1.0f - wy1f;
        const float* img = feat + ((size_t)b * FCH + c) * FPX;
        float acc = 0.f;
#define TAPF(XC, YC, WV) { \
        float xf = (XC), yf = (YC); \
        float valid = (xf >= 0.f && xf <= 127.f && yf >= 0.f && yf <= 127.f) ? 1.f : 0.f; \
        int xi = (int)fminf(fmaxf(xf, 0.f), 127.f); \
        int yi = (int)fminf(fmaxf(yf, 0.f), 127.f); \
        acc += img[yi * 128 + xi] * ((WV) * valid); }
        TAPF(x0f,        y0f,        wx0f * wy0f)
        TAPF(x0f + 1.0f, y0f,        wx1f * wy0f)
        TAPF(x0f,        y0f + 1.0f, wx0f * wy1f)
        TAPF(x0f + 1.0f, y0f + 1.0f, wx1f * wy1f)
#undef TAPF
        Fl[p][c + 3] = acc;
    }
    __syncthreads();

    {   // layer 1: 515(+1 pad) -> 256, relu
        int o = tid;
        float acc[PB];
#pragma unroll
        for (int p = 0; p < PB; ++p) acc[p] = 0.f;
        for (int c4 = 0; c4 < FSTR / 4; ++c4) {
            float wa = wt1[(c4 * 4 + 0) * HID + o];
            float wb = wt1[(c4 * 4 + 1) * HID + o];
            float wc = wt1[(c4 * 4 + 2) * HID + o];
            float wd = wt1[(c4 * 4 + 3) * HID + o];
#pragma unroll
            for (int p = 0; p < PB; ++p) {
                float4 f = *(const float4*)&Fl[p][c4 * 4];
                acc[p] = fmaf(wa, f.x, acc[p]);
                acc[p] = fmaf(wb, f.y, acc[p]);
                acc[p] = fmaf(wc, f.z, acc[p]);
                acc[p] = fmaf(wd, f.w, acc[p]);
            }
        }
#pragma unroll
        for (int p = 0; p < PB; ++p) hA[p][o] = fmaxf(acc[p], 0.f);
    }
    __syncthreads();
    {   // layer 2
        int o = tid;
        float acc[PB];
#pragma unroll
        for (int p = 0; p < PB; ++p) acc[p] = 0.f;
        for (int c4 = 0; c4 < HID / 4; ++c4) {
            float wa = wt2[(c4 * 4 + 0) * HID + o];
            float wb = wt2[(c4 * 4 + 1) * HID + o];
            float wc = wt2[(c4 * 4 + 2) * HID + o];
            float wd = wt2[(c4 * 4 + 3) * HID + o];
#pragma unroll
            for (int p = 0; p < PB; ++p) {
                float4 f = *(const float4*)&hA[p][c4 * 4];
                acc[p] = fmaf(wa, f.x, acc[p]);
                acc[p] = fmaf(wb, f.y, acc[p]);
                acc[p] = fmaf(wc, f.z, acc[p]);
                acc[p] = fmaf(wd, f.w, acc[p]);
            }
        }
#pragma unroll
        for (int p = 0; p < PB; ++p) hB[p][o] = fmaxf(acc[p], 0.f);
    }
    __syncthreads();
    {   // layer 3
        int o = tid;
        float acc[PB];
#pragma unroll
        for (int p = 0; p < PB; ++p) acc[p] = 0.f;
        for (int c4 = 0; c4 < HID / 4; ++c4) {
            float wa = wt3[(c4 * 4 + 0) * HID + o];
            float wb = wt3[(c4 * 4 + 1) * HID + o];
            float wc = wt3[(c4 * 4 + 2) * HID + o];
            float wd = wt3[(c4 * 4 + 3) * HID + o];
#pragma unroll
            for (int p = 0; p < PB; ++p) {
                float4 f = *(const float4*)&hB[p][c4 * 4];
                acc[p] = fmaf(wa, f.x, acc[p]);
                acc[p] = fmaf(wb, f.y, acc[p]);
                acc[p] = fmaf(wc, f.z, acc[p]);
                acc[p] = fmaf(wd, f.w, acc[p]);
            }
        }
#pragma unroll
        for (int p = 0; p < PB; ++p) hA[p][o] = fmaxf(acc[p], 0.f);
    }
    __syncthreads();
    if (tid < 3 * PB) {  // layer 4: 256 -> 3, + b4
        int o = tid % 3, p = tid / 3;
        float acc = 0.f;
        const float* wr = w4 + (size_t)o * HID;
        for (int c = 0; c < HID; ++c) acc += wr[c] * hA[p][c];
        acc += b4[o];
        int gp = p0 + p;
        int b = gp / NP, n = gp % NP;
        rend[(size_t)b * (NCLS * NP) + o * NP + n] = acc;
    }
}

extern "C" void kernel_launch(void* const* d_in, const int* in_sizes, int n_in,
                              void* d_out, int out_size, void* d_ws, size_t ws_size,
                              hipStream_t stream) {
    // inputs: 0:x(unused) 1:feature 2:mask 3:over_gen 4:coverage 5:w1 6:w2 7:w3 8:w4 9:b4
    const float* feature  = (const float*)d_in[1];
    const float* mask     = (const float*)d_in[2];
    const float* over_gen = (const float*)d_in[3];
    const float* coverage = (const float*)d_in[4];
    const float* w1 = (const float*)d_in[5];
    const float* w2 = (const float*)d_in[6];
    const float* w3 = (const float*)d_in[7];
    const float* w4 = (const float*)d_in[8];
    const float* b4 = (const float*)d_in[9];
    float* out = (float*)d_out;
    float* ws  = (float*)d_ws;

    float* uws = ws + WS_U;
    float* pts = ws + WS_PTS;
    float* wt1 = ws + WS_WT1;
    float* wt2 = ws + WS_WT2;
    float* wt3 = ws + WS_WT3;
    int*   hst = (int*)(ws + WS_HIST);

    // out layout: rend[4800] | points[3200] | mask[49152]
    float* out_rend = out;
    float* out_pts  = out + 4800;
    float* out_mask = out + 8000;

    k_u<<<GRID_U, 1024, 0, stream>>>(mask, over_gen, w1, w2, w3,
                                     uws, hst, wt1, wt2, wt3, out_mask);
    k_sel<<<B, 1024, 0, stream>>>(uws, over_gen, coverage, hst, pts, out_pts);
    k_back<<<(B * NP) / PB, 256, 0, stream>>>(mask, feature, pts,
                                              wt1, wt2, wt3, w4, b4, out_rend);
}